// Round 2
// baseline (727.340 us; speedup 1.0000x reference)
//
#include <hip/hip_runtime.h>

// LinearAttentionBlock: H(4,8192,1024) f32
// qkv = H@Wqkv^T + b; q,k = elu+1; per (b,h): kv = K^T V, k1 = sum k
// out = (q@kv)/(q.k1); scrambled reshape; @Wproj^T + b; LN; + residual
//
// Pipeline: cvt->bf16, MFMA GEMM1 (fused bias+phi, bf16 out), split-K kv
// partials + reduce, apply+scramble (bf16 out), MFMA GEMM2 (f32 out),
// LN+residual fused.

typedef __attribute__((ext_vector_type(4))) float f32x4;
typedef __attribute__((ext_vector_type(8))) short bf16x8;

__device__ __forceinline__ unsigned short f2b(float f) {
    unsigned u = __float_as_uint(f);
    u = (u + 0x7FFFu + ((u >> 16) & 1u)) >> 16;  // RNE
    return (unsigned short)u;
}
__device__ __forceinline__ float b2f(unsigned short h) {
    return __uint_as_float(((unsigned)h) << 16);
}

// ---------------- fp32 -> bf16 conversion (vectorized, grid-stride) -------
__global__ __launch_bounds__(256) void cvt_f32_bf16(const float* __restrict__ in,
                                                    unsigned short* __restrict__ out,
                                                    long n4) {
    long i = (long)blockIdx.x * 256 + threadIdx.x;
    long stride = (long)gridDim.x * 256;
    for (; i < n4; i += stride) {
        float4 v = ((const float4*)in)[i];
        ushort4 o;
        o.x = f2b(v.x); o.y = f2b(v.y); o.z = f2b(v.z); o.w = f2b(v.w);
        ((ushort4*)out)[i] = o;
    }
}

// ---------------- bf16 MFMA GEMM, C = A @ B^T (+bias) ---------------------
// A: M x K bf16 row-major; B: N x K bf16 row-major (K-major both).
// 128x128 tile, BK=64, 4 waves (2x2), each wave 64x64 via 4x4 16x16x32 mfma.
// MODE 0: epilogue v+=bias; if col<2048 v=phi(v); store bf16  (QKV gemm)
// MODE 1: epilogue v+=bias; store f32                          (proj gemm)
template<int MODE>
__global__ __launch_bounds__(256) void gemm_bt(const unsigned short* __restrict__ A,
                                               const unsigned short* __restrict__ B,
                                               const float* __restrict__ bias,
                                               void* __restrict__ Cout,
                                               int M, int N, int K) {
    __shared__ unsigned short As[128][72];  // +8 pad: 2-way bank alias (free)
    __shared__ unsigned short Bs[128][72];
    const int tid = threadIdx.x;
    const int bn = blockIdx.x, bm = blockIdx.y;
    const int wave = tid >> 6, lane = tid & 63;
    const int wr = wave >> 1, wc = wave & 1;
    const int lr = lane & 15, lk = lane >> 4;
    f32x4 acc[4][4] = {};

    const size_t arow0 = (size_t)bm * 128;
    const size_t brow0 = (size_t)bn * 128;

    for (int k0 = 0; k0 < K; k0 += 64) {
#pragma unroll
        for (int i = 0; i < 4; ++i) {
            int c = tid + i * 256;       // 1024 chunks of 8 bf16 per matrix
            int row = c >> 3, cg = c & 7;
            uint4 va = *(const uint4*)(A + (arow0 + row) * K + k0 + cg * 8);
            *(uint4*)(&As[row][cg * 8]) = va;
            uint4 vb = *(const uint4*)(B + (brow0 + row) * K + k0 + cg * 8);
            *(uint4*)(&Bs[row][cg * 8]) = vb;
        }
        __syncthreads();
#pragma unroll
        for (int ks = 0; ks < 2; ++ks) {
            bf16x8 af[4], bfr[4];
#pragma unroll
            for (int mi = 0; mi < 4; ++mi)
                af[mi] = *(const bf16x8*)(&As[wr * 64 + mi * 16 + lr][ks * 32 + lk * 8]);
#pragma unroll
            for (int ni = 0; ni < 4; ++ni)
                bfr[ni] = *(const bf16x8*)(&Bs[wc * 64 + ni * 16 + lr][ks * 32 + lk * 8]);
#pragma unroll
            for (int mi = 0; mi < 4; ++mi)
#pragma unroll
                for (int ni = 0; ni < 4; ++ni)
                    acc[mi][ni] = __builtin_amdgcn_mfma_f32_16x16x32_bf16(
                        af[mi], bfr[ni], acc[mi][ni], 0, 0, 0);
        }
        __syncthreads();
    }
    // epilogue: C/D layout col=lane&15, row=(lane>>4)*4+reg  [m89-verified]
#pragma unroll
    for (int mi = 0; mi < 4; ++mi) {
#pragma unroll
        for (int ni = 0; ni < 4; ++ni) {
            int col = (int)brow0 + wc * 64 + ni * 16 + lr;
            float bv = bias[col];
#pragma unroll
            for (int r = 0; r < 4; ++r) {
                size_t row = arow0 + wr * 64 + mi * 16 + lk * 4 + r;
                float v = acc[mi][ni][r] + bv;
                if (MODE == 0) {
                    if (col < 2048) v = (v > 0.f) ? (v + 1.f) : __expf(v);  // elu+1
                    ((unsigned short*)Cout)[row * (size_t)N + col] = f2b(v);
                } else {
                    ((float*)Cout)[row * (size_t)N + col] = v;
                }
            }
        }
    }
}

// ---------------- kv split-K partials: per (b,h,chunk of 1024 rows) -------
// part[(bh*8+chunk)] = [64x64 kv | 64 k1]  (4160 floats)
__global__ __launch_bounds__(256) void kv_partial(const unsigned short* __restrict__ qkv,
                                                  float* __restrict__ part) {
    const int bh = blockIdx.x, chunk = blockIdx.y;
    const int b = bh >> 4, h = bh & 15;
    __shared__ unsigned short kb[16][64];
    __shared__ unsigned short vb[16][64];
    const int tid = threadIdx.x;
    const int d0 = (tid >> 4) * 4, v0 = (tid & 15) * 4;
    float acc[4][4] = {};
    float k1a[4] = {0.f, 0.f, 0.f, 0.f};
    const size_t base = ((size_t)b * 8192 + (size_t)chunk * 1024) * 3072;
    const int nn = tid >> 4;          // staged row 0..15
    const int which = (tid >> 3) & 1; // 0: k, 1: v
    const int cg = tid & 7;           // 8-elem group
    const size_t loff = base + (size_t)nn * 3072 + (which ? 2048 : 1024) + h * 64 + cg * 8;

    for (int n0 = 0; n0 < 1024; n0 += 16) {
        uint4 val = *(const uint4*)(qkv + loff + (size_t)n0 * 3072);
        if (which) *(uint4*)(&vb[nn][cg * 8]) = val;
        else       *(uint4*)(&kb[nn][cg * 8]) = val;
        __syncthreads();
#pragma unroll 4
        for (int j = 0; j < 16; ++j) {
            ushort4 ku = *(const ushort4*)(&kb[j][d0]);
            ushort4 vu = *(const ushort4*)(&vb[j][v0]);
            float kd[4] = {b2f(ku.x), b2f(ku.y), b2f(ku.z), b2f(ku.w)};
            float vd[4] = {b2f(vu.x), b2f(vu.y), b2f(vu.z), b2f(vu.w)};
#pragma unroll
            for (int i = 0; i < 4; ++i)
#pragma unroll
                for (int jj = 0; jj < 4; ++jj)
                    acc[i][jj] += kd[i] * vd[jj];
            if ((tid & 15) == 0)
#pragma unroll
                for (int i = 0; i < 4; ++i) k1a[i] += kd[i];
        }
        __syncthreads();
    }
    float* dst = part + ((size_t)bh * 8 + chunk) * 4160;
#pragma unroll
    for (int i = 0; i < 4; ++i)
#pragma unroll
        for (int jj = 0; jj < 4; ++jj)
            dst[(d0 + i) * 64 + v0 + jj] = acc[i][jj];
    if ((tid & 15) == 0)
#pragma unroll
        for (int i = 0; i < 4; ++i) dst[4096 + d0 + i] = k1a[i];
}

__global__ __launch_bounds__(256) void kv_reduce(const float* __restrict__ part,
                                                 float* __restrict__ kvk1) {
    const int bh = blockIdx.x;
    for (int idx = threadIdx.x; idx < 4160; idx += 256) {
        float s = 0.f;
#pragma unroll
        for (int c = 0; c < 8; ++c) s += part[((size_t)bh * 8 + c) * 4160 + idx];
        kvk1[(size_t)bh * 4160 + idx] = s;
    }
}

// ---------------- apply: out = (q@kv)/max(q.k1,1e-6), scrambled write -----
// block: 64 n-rows; thread t: row r=t>>2, col quarter qt=t&3 (16 outputs)
__global__ __launch_bounds__(256) void apply_attn(const unsigned short* __restrict__ qkv,
                                                  const float* __restrict__ kvk1,
                                                  unsigned short* __restrict__ att) {
    const int nblk = blockIdx.x;
    const int bh = blockIdx.y;
    const int b = bh >> 4, h = bh & 15;
    __shared__ float kvs[64][64];
    __shared__ float k1s[64];
    const float* src = kvk1 + (size_t)bh * 4160;
    for (int i = threadIdx.x; i < 4096; i += 256) kvs[i >> 6][i & 63] = src[i];
    if (threadIdx.x < 64) k1s[threadIdx.x] = src[4096 + threadIdx.x];
    __syncthreads();
    const int t = threadIdx.x;
    const int r = t >> 2, qt = t & 3;
    const int n = nblk * 64 + r;
    const unsigned short* qrow = qkv + ((size_t)b * 8192 + n) * 3072 + h * 64;
    float acc[16] = {};
    float qk1 = 0.f;
    for (int dc = 0; dc < 64; dc += 8) {
        uint4 qu = *(const uint4*)(qrow + dc);
        unsigned qw[4] = {qu.x, qu.y, qu.z, qu.w};
#pragma unroll
        for (int jj = 0; jj < 8; ++jj) {
            float qd = (jj & 1) ? __uint_as_float(qw[jj >> 1] & 0xFFFF0000u)
                                : __uint_as_float(qw[jj >> 1] << 16);
            int d = dc + jj;
            qk1 += qd * k1s[d];
            const float4* kr = (const float4*)(&kvs[d][qt * 16]);  // 4-addr broadcast
            float4 c0 = kr[0], c1 = kr[1], c2 = kr[2], c3 = kr[3];
            acc[0]  += qd * c0.x; acc[1]  += qd * c0.y; acc[2]  += qd * c0.z; acc[3]  += qd * c0.w;
            acc[4]  += qd * c1.x; acc[5]  += qd * c1.y; acc[6]  += qd * c1.z; acc[7]  += qd * c1.w;
            acc[8]  += qd * c2.x; acc[9]  += qd * c2.y; acc[10] += qd * c2.z; acc[11] += qd * c2.w;
            acc[12] += qd * c3.x; acc[13] += qd * c3.y; acc[14] += qd * c3.z; acc[15] += qd * c3.w;
        }
    }
    float rinv = 1.f / fmaxf(qk1, 1e-6f);
    union { unsigned short us[16]; uint4 u4[2]; } ob;
#pragma unroll
    for (int j = 0; j < 16; ++j) ob.us[j] = f2b(acc[j] * rinv);
    // bug-faithful reshape: (h,n,dd) -> row h*512 + n/16, col (n%16)*64 + dd
    unsigned short* dst = att + (((size_t)b * 8192) + h * 512 + (n >> 4)) * 1024
                              + (n & 15) * 64 + qt * 16;
    *(uint4*)dst = ob.u4[0];
    *(uint4*)(dst + 8) = ob.u4[1];
}

// ---------------- LayerNorm + residual ------------------------------------
__global__ __launch_bounds__(256) void ln_residual(const float* __restrict__ X,
                                                   const float* __restrict__ H,
                                                   const float* __restrict__ gamma,
                                                   const float* __restrict__ beta,
                                                   float* __restrict__ out) {
    const size_t row = blockIdx.x;
    const int tid = threadIdx.x;
    const float* x = X + row * 1024;
    float v[4];
    float s = 0.f, s2 = 0.f;
#pragma unroll
    for (int i = 0; i < 4; ++i) {
        v[i] = x[tid + i * 256];
        s += v[i];
        s2 += v[i] * v[i];
    }
#pragma unroll
    for (int o = 32; o > 0; o >>= 1) {
        s  += __shfl_xor(s, o, 64);
        s2 += __shfl_xor(s2, o, 64);
    }
    __shared__ float rs[4], rs2[4];
    const int wave = tid >> 6;
    if ((tid & 63) == 0) { rs[wave] = s; rs2[wave] = s2; }
    __syncthreads();
    s  = rs[0] + rs[1] + rs[2] + rs[3];
    s2 = rs2[0] + rs2[1] + rs2[2] + rs2[3];
    float mu = s * (1.f / 1024.f);
    float var = s2 * (1.f / 1024.f) - mu * mu;   // biased var (jnp.var)
    float inv = rsqrtf(var + 1e-5f);
    const float* hrow = H + row * 1024;
    float* orow = out + row * 1024;
#pragma unroll
    for (int i = 0; i < 4; ++i) {
        int c = tid + i * 256;
        orow[c] = (v[i] - mu) * inv * gamma[c] + beta[c] + hrow[c];
    }
}

// ---------------------------------------------------------------------------
extern "C" void kernel_launch(void* const* d_in, const int* in_sizes, int n_in,
                              void* d_out, int out_size, void* d_ws, size_t ws_size,
                              hipStream_t stream) {
    const float* H     = (const float*)d_in[0];
    const float* Wqkv  = (const float*)d_in[1];
    const float* bqkv  = (const float*)d_in[2];
    const float* Wproj = (const float*)d_in[3];
    const float* bproj = (const float*)d_in[4];
    const float* gamma = (const float*)d_in[5];
    const float* beta  = (const float*)d_in[6];
    float* out = (float*)d_out;
    char* ws = (char*)d_ws;

    // ws layout (bytes); att aliases Hbf, out2 aliases qkv_bf (disjoint lifetimes)
    unsigned short* wq_bf = (unsigned short*)(ws);                 //   6,291,456
    unsigned short* wp_bf = (unsigned short*)(ws + 6291456);       //   2,097,152
    unsigned short* hbf   = (unsigned short*)(ws + 8388608);       //  67,108,864
    unsigned short* att   = hbf;
    unsigned short* qkvbf = (unsigned short*)(ws + 75497472);      // 201,326,592
    float*          out2  = (float*)(ws + 75497472);
    float*          kvk1  = (float*)(ws + 276824064);              //   1,064,960
    float*          part  = (float*)(ws + 277889024);              //   8,519,680
                                                                   // total ~286.4 MB

    cvt_f32_bf16<<<2048, 256, 0, stream>>>(H, hbf, 33554432 / 4);
    cvt_f32_bf16<<<256, 256, 0, stream>>>(Wqkv, wq_bf, 3145728 / 4);
    cvt_f32_bf16<<<128, 256, 0, stream>>>(Wproj, wp_bf, 1048576 / 4);

    gemm_bt<0><<<dim3(24, 256), 256, 0, stream>>>(hbf, wq_bf, bqkv, (void*)qkvbf,
                                                  32768, 3072, 1024);

    kv_partial<<<dim3(64, 8), 256, 0, stream>>>(qkvbf, part);
    kv_reduce<<<64, 256, 0, stream>>>(part, kvk1);

    apply_attn<<<dim3(128, 64), 256, 0, stream>>>(qkvbf, kvk1, att);

    gemm_bt<1><<<dim3(8, 256), 256, 0, stream>>>(att, wp_bf, bproj, (void*)out2,
                                                 32768, 1024, 1024);

    ln_residual<<<32768, 256, 0, stream>>>(out2, H, gamma, beta, out);
}